// Round 3
// baseline (834.420 us; speedup 1.0000x reference)
//
#include <hip/hip_runtime.h>
#include <cstdint>

#define NBOX 12288
#define NWORDS 192
#define POS_THRESH 0.15f
#define NMS_THRESH 0.7f

typedef unsigned long long u64;
typedef _Float16 half8 __attribute__((ext_vector_type(8)));
typedef float floatx4 __attribute__((ext_vector_type(4)));

// ---------------- Kernel 0a: zero the conv accumulator ----------------
__global__ __launch_bounds__(256) void zero_y(float4* __restrict__ Y) {
  Y[blockIdx.x * 256 + threadIdx.x] = float4{0.f, 0.f, 0.f, 0.f};
}

// ---------------- Kernel 0b: W (3,3,1024,512) -> WT[tap][n][c] fp16 h/l split ----------------
// l pre-scaled by 4096 so it stays in fp16 normal range (w~0.01 -> wl~2e-6 would be denormal).
__global__ __launch_bounds__(256) void prep_wt(
    const float* __restrict__ Wc, _Float16* __restrict__ WTh, _Float16* __restrict__ WTl)
{
  __shared__ float tile[64][65];
  const int b = blockIdx.x;           // 9 taps * 16 c-tiles * 8 n-tiles = 1152
  const int tap = b >> 7;
  const int rem = b & 127;
  const int c0 = (rem >> 3) * 64, n0 = (rem & 7) * 64;
  const int t = threadIdx.x;
  #pragma unroll
  for (int i = 0; i < 16; ++i) {
    const int idx = i * 256 + t;
    const int c = idx >> 6, n = idx & 63;
    tile[n][c] = Wc[((size_t)(tap * 1024 + c0 + c)) * 512 + n0 + n];
  }
  __syncthreads();
  #pragma unroll
  for (int i = 0; i < 16; ++i) {
    const int idx = i * 256 + t;
    const int n = idx >> 6, c = idx & 63;
    const float v = tile[n][c];
    const _Float16 h = (_Float16)v;
    const _Float16 l = (_Float16)((v - (float)h) * 4096.0f);
    const size_t o = ((size_t)(tap * 512 + n0 + n)) * 1024 + c0 + c;
    WTh[o] = h;
    WTl[o] = l;
  }
}

// ---------------- Kernel 1: 3x3 conv via split-fp16 MFMA ----------------
#define AROW 40                 // 32 k-halves padded to 40 (80B = 20 banks: 2-way only)
#define AS_PLANE (4 * 66 * AROW)
#define BS_PLANE (128 * AROW)
__global__ __launch_bounds__(256, 1) void conv_mfma(
    const float* __restrict__ X, const _Float16* __restrict__ WTh,
    const _Float16* __restrict__ WTl, float* __restrict__ Y)
{
  __shared__ _Float16 As[2 * AS_PLANE];   // 42,240 B
  __shared__ _Float16 Bs[2 * BS_PLANE];   // 20,480 B
  const int bid = blockIdx.x;
  const int ks = bid & 1;
  const int nt = (bid >> 1) & 3;
  const int mt = bid >> 3;
  const int t = threadIdx.x;
  const int lane = t & 63, wid = t >> 6;
  const int wm = wid >> 1, wn = wid & 1;
  const int lrow = lane & 15, quad = lane >> 4;

  floatx4 accH[4][4], accL[4][4];
  #pragma unroll
  for (int i = 0; i < 4; ++i)
    #pragma unroll
    for (int j = 0; j < 4; ++j) { accH[i][j] = (floatx4)0.f; accL[i][j] = (floatx4)0.f; }

  for (int kc = 0; kc < 16; ++kc) {
    const int c0 = ks * 512 + kc * 32;
    __syncthreads();   // prior chunk readers done
    // ---- stage A halo: 264 (yy,xx) rows x 32 ch, split to h/l ----
    for (int r = t; r < 264; r += 256) {
      const int yy = r / 66;
      const int xx = r - yy * 66;
      const int yi = mt * 2 + yy - 1;
      const int xi = xx - 1;
      _Float16* dsth = &As[(yy * 66 + xx) * AROW];
      _Float16* dstl = dsth + AS_PLANE;
      if (yi >= 0 && yi < 64 && xi >= 0 && xi < 64) {
        const float4* src = (const float4*)(X + ((size_t)(yi * 64 + xi)) * 1024 + c0);
        #pragma unroll
        for (int j = 0; j < 4; ++j) {
          const float4 va = src[2 * j], vb = src[2 * j + 1];
          const float f[8] = {va.x, va.y, va.z, va.w, vb.x, vb.y, vb.z, vb.w};
          half8 hh, hl;
          #pragma unroll
          for (int e = 0; e < 8; ++e) {
            const _Float16 h = (_Float16)f[e];
            hh[e] = h;
            hl[e] = (_Float16)((f[e] - (float)h) * 4096.0f);
          }
          *(half8*)&dsth[j * 8] = hh;
          *(half8*)&dstl[j * 8] = hl;
        }
      } else {
        const half8 z = (half8)(_Float16)0.f;
        #pragma unroll
        for (int j = 0; j < 4; ++j) { *(half8*)&dsth[j * 8] = z; *(half8*)&dstl[j * 8] = z; }
      }
    }
    for (int tap = 0; tap < 9; ++tap) {
      if (tap > 0) __syncthreads();   // prior tap's B readers done
      {   // ---- stage B: 256 rows (hl,n) x 32 halves ----
        const int hl = t >> 7, n = t & 127;
        const _Float16* src = (hl ? WTl : WTh) +
            ((size_t)(tap * 512 + nt * 128 + n)) * 1024 + c0;
        _Float16* dst = &Bs[hl * BS_PLANE + n * AROW];
        #pragma unroll
        for (int j = 0; j < 4; ++j)
          *(half8*)&dst[j * 8] = *(const half8*)&src[j * 8];
      }
      __syncthreads();   // A (first tap) + B visible
      const int dy = tap / 3 - 1, dx = tap - (tap / 3) * 3 - 1;
      const int yy = wm + dy + 1;
      const int xxb = dx + 1;
      half8 Ah[4], Al[4], Bh[4], Bl[4];
      #pragma unroll
      for (int fm = 0; fm < 4; ++fm) {
        const int idx = (yy * 66 + xxb + fm * 16 + lrow) * AROW + quad * 8;
        Ah[fm] = *(const half8*)&As[idx];
        Al[fm] = *(const half8*)&As[idx + AS_PLANE];
      }
      #pragma unroll
      for (int fn = 0; fn < 4; ++fn) {
        const int idx = (wn * 64 + fn * 16 + lrow) * AROW + quad * 8;
        Bh[fn] = *(const half8*)&Bs[idx];
        Bl[fn] = *(const half8*)&Bs[idx + BS_PLANE];
      }
      #pragma unroll
      for (int fm = 0; fm < 4; ++fm)
        #pragma unroll
        for (int fn = 0; fn < 4; ++fn) {
          accH[fm][fn] = __builtin_amdgcn_mfma_f32_16x16x32_f16(Ah[fm], Bh[fn], accH[fm][fn], 0, 0, 0);
          accL[fm][fn] = __builtin_amdgcn_mfma_f32_16x16x32_f16(Al[fm], Bh[fn], accL[fm][fn], 0, 0, 0);
          accL[fm][fn] = __builtin_amdgcn_mfma_f32_16x16x32_f16(Ah[fm], Bl[fn], accL[fm][fn], 0, 0, 0);
        }
    }
  }
  // ---- epilogue: combine scales, atomic-accumulate (2 K-slices per output) ----
  const int m0 = mt * 128 + wm * 64;
  const int n0 = nt * 128 + wn * 64;
  #pragma unroll
  for (int fm = 0; fm < 4; ++fm)
    #pragma unroll
    for (int fn = 0; fn < 4; ++fn) {
      const int n = n0 + fn * 16 + lrow;
      #pragma unroll
      for (int r = 0; r < 4; ++r) {
        const int m = m0 + fm * 16 + quad * 4 + r;
        atomicAdd(&Y[(size_t)m * 512 + n],
                  accH[fm][fn][r] + accL[fm][fn][r] * (1.0f / 4096.0f));
      }
    }
}

// ---------------- Kernel 2: bias+ReLU + 1x1 heads + softmax(6) + decode + ext init ----------------
__global__ __launch_bounds__(64) void heads_decode(
    const float* __restrict__ Yx, const float* __restrict__ Bc,
    const float* __restrict__ Wcls, const float* __restrict__ bcls,
    const float* __restrict__ Wreg, const float* __restrict__ breg,
    float* __restrict__ boxes, float* __restrict__ scores, int* __restrict__ ext)
{
  __shared__ float xs[512];
  const int pos = blockIdx.x;
  const int l = threadIdx.x;
  if (l == 0 && pos < NWORDS) ext[pos] = pos;
  const float* xrow = Yx + (size_t)pos * 512;
  float4 v0 = *(const float4*)&xrow[l * 8];
  float4 v1 = *(const float4*)&xrow[l * 8 + 4];
  const float4 b0 = *(const float4*)&Bc[l * 8];
  const float4 b1 = *(const float4*)&Bc[l * 8 + 4];
  xs[l * 8 + 0] = fmaxf(v0.x + b0.x, 0.f);
  xs[l * 8 + 1] = fmaxf(v0.y + b0.y, 0.f);
  xs[l * 8 + 2] = fmaxf(v0.z + b0.z, 0.f);
  xs[l * 8 + 3] = fmaxf(v0.w + b0.w, 0.f);
  xs[l * 8 + 4] = fmaxf(v1.x + b1.x, 0.f);
  xs[l * 8 + 5] = fmaxf(v1.y + b1.y, 0.f);
  xs[l * 8 + 6] = fmaxf(v1.z + b1.z, 0.f);
  xs[l * 8 + 7] = fmaxf(v1.w + b1.w, 0.f);
  __syncthreads();

  const float* wp;
  int oc;
  float bini;
  if (l < 6)       { wp = Wcls + l;       oc = 6;  bini = bcls[l]; }
  else if (l < 18) { wp = Wreg + (l - 6); oc = 12; bini = breg[l - 6]; }
  else             { wp = Wcls;           oc = 0;  bini = 0.f; }
  float acc = bini;
  const float* p = wp;
  #pragma unroll 4
  for (int c = 0; c < 512; ++c) { acc = fmaf(xs[c], *p, acc); p += oc; }

  const float l0 = __shfl(acc, 0), l1 = __shfl(acc, 1), l2 = __shfl(acc, 2);
  const float l3 = __shfl(acc, 3), l4 = __shfl(acc, 4), l5 = __shfl(acc, 5);
  const int a = (l < 3) ? l : 0;
  const float d0 = __shfl(acc, 6 + a * 4 + 0);
  const float d1 = __shfl(acc, 6 + a * 4 + 1);
  const float d2 = __shfl(acc, 6 + a * 4 + 2);
  const float d3 = __shfl(acc, 6 + a * 4 + 3);

  const float mx = fmaxf(fmaxf(fmaxf(l0, l1), fmaxf(l2, l3)), fmaxf(l4, l5));
  const float e0 = expf(l0 - mx), e1 = expf(l1 - mx), e2 = expf(l2 - mx);
  const float e3 = expf(l3 - mx), e4 = expf(l4 - mx), e5 = expf(l5 - mx);
  const float den = ((((e0 + e1) + e2) + e3) + e4) + e5;
  const float esel = (a == 0) ? e1 : ((a == 1) ? e3 : e5);
  const float sc = esel / den;

  const int px = pos & 63, py = pos >> 6;
  const float cx = (px + 0.5f) * 16.0f;
  const float cy = (py + 0.5f) * 16.0f;
  const float ratio = (a == 0) ? 0.5f : ((a == 1) ? 1.0f : 2.0f);
  const float sq = sqrtf(ratio);
  const float wsz = 128.0f * sq;
  const float hsz = 128.0f / sq;
  const float a0 = cx - wsz * 0.5f;
  const float a1 = cy - hsz * 0.5f;
  const float a2 = cx + wsz * 0.5f;
  const float a3 = cy + hsz * 0.5f;
  const float w = a2 - a0, h = a3 - a1;
  const float xc = __fadd_rn(__fmul_rn(__fadd_rn(a0, a2), 0.5f), __fmul_rn(d0, w));
  const float yc = __fadd_rn(__fmul_rn(__fadd_rn(a1, a3), 0.5f), __fmul_rn(d1, h));
  const float nw = __fmul_rn(w, expf(d2));
  const float nh = __fmul_rn(h, expf(d3));
  float4 box;
  box.x = __fsub_rn(xc, __fmul_rn(nw, 0.5f));
  box.y = __fsub_rn(yc, __fmul_rn(nh, 0.5f));
  box.z = __fadd_rn(xc, __fmul_rn(nw, 0.5f));
  box.w = __fadd_rn(yc, __fmul_rn(nh, 0.5f));

  if (l < 3) {
    const int idx = pos * 3 + a;
    *(float4*)&boxes[idx * 4] = box;
    scores[idx] = sc;
  }
}

// ---------------- Kernel 3: suppression bit-matrix (column-major) + extent ----------------
__global__ __launch_bounds__(256) void build_mask(
    const float* __restrict__ boxes, u64* __restrict__ maskT,
    int* __restrict__ ext)
{
  const int w  = blockIdx.x;
  const int ci = blockIdx.y;
  if (w < ci) return;
  __shared__ float4 rb[64];
  __shared__ int anyf;
  const int t = threadIdx.x;
  const int lane = t & 63, wid = t >> 6;
  if (t == 0) anyf = 0;
  if (t < 64) rb[t] = *(const float4*)&boxes[(ci * 64 + t) * 4];
  const float4 cb = *(const float4*)&boxes[(w * 64 + lane) * 4];
  const float careaa = __fmul_rn(cb.z - cb.x, cb.w - cb.y);
  const int jglob = w * 64 + lane;
  __syncthreads();
  bool any = false;
  for (int rr = 0; rr < 16; ++rr) {
    const int r = wid * 16 + rr;
    const int row = ci * 64 + r;
    const float4 rx = rb[r];
    const float ra = __fmul_rn(rx.z - rx.x, rx.w - rx.y);
    const float xx1 = fmaxf(rx.x, cb.x);
    const float yy1 = fmaxf(rx.y, cb.y);
    const float xx2 = fminf(rx.z, cb.z);
    const float yy2 = fminf(rx.w, cb.w);
    const float iw = fmaxf(__fsub_rn(xx2, xx1), 0.f);
    const float ih = fmaxf(__fsub_rn(yy2, yy1), 0.f);
    const float inter = __fmul_rn(iw, ih);
    const float den = __fadd_rn(__fsub_rn(__fadd_rn(ra, careaa), inter), 1e-9f);
    const float iou = __fdiv_rn(inter, den);
    const bool bit = (iou > NMS_THRESH) && (jglob > row);
    any |= bit;
    const u64 word = __ballot(bit ? 1 : 0);
    if (lane == 0) maskT[(size_t)w * NBOX + row] = word;
  }
  if (any) anyf = 1;
  __syncthreads();
  if (t == 0 && anyf && w > ci) atomicMax(&ext[ci], w);
}

// ---------------- Kernel 4: sequential greedy NMS scan (single WAVE) ----------------
// v5: single wave, zero LDS, zero barriers.
//  - alive/ext live in registers distributed across lanes (lane l owns words l, l+64, l+128).
//  - intra-word greedy: ballot-computed S = {b in aw0 : dg[b] & aw0 != 0}. If S empty
//    (common: suppression is sparse), aw = aw0 instantly; else 4-wide scalar chain over
//    S only (provably exact: non-S bits add nothing to supp within aw0).
//  - cross-word: 8 columns prefetched 3 iterations ahead (4 static buffer sets, unroll-4,
//    no rotation movs -> no vmcnt(0) drain); per-lane select + shfl_xor OR-reduce +
//    shfl scatter to owner lane. Overflow (ext-c > 8) loads synchronously (rare).
__device__ __forceinline__ u64 rl64v(u64 v, int ln) {
  const unsigned a = (unsigned)__builtin_amdgcn_readlane((int)(unsigned)v, ln);
  const unsigned b = (unsigned)__builtin_amdgcn_readlane((int)(unsigned)(v >> 32), ln);
  return ((u64)b << 32) | (u64)a;
}
__device__ __forceinline__ u64 shfl64(u64 v, int src) {
  const int lo = __shfl((int)(unsigned)v, src);
  const int hi = __shfl((int)(unsigned)(v >> 32), src);
  return ((u64)(unsigned)hi << 32) | (unsigned)lo;
}
__device__ __forceinline__ u64 shflxor64(u64 v, int m) {
  const int lo = __shfl_xor((int)(unsigned)v, m);
  const int hi = __shfl_xor((int)(unsigned)(v >> 32), m);
  return ((u64)(unsigned)hi << 32) | (unsigned)lo;
}
__device__ __forceinline__ u64 build_alive(const float* sp) {
  u64 w = 0ull;
  const float4* p = (const float4*)sp;
  #pragma unroll
  for (int q = 0; q < 16; ++q) {
    const float4 s = p[q];
    if (s.x > POS_THRESH) w |= (1ull << (q * 4 + 0));
    if (s.y > POS_THRESH) w |= (1ull << (q * 4 + 1));
    if (s.z > POS_THRESH) w |= (1ull << (q * 4 + 2));
    if (s.w > POS_THRESH) w |= (1ull << (q * 4 + 3));
  }
  return w;
}
__device__ __forceinline__ int read_ext3(int e0, int e1, int e2, int w) {
  const int kk = w >> 6;
  const int v = (kk == 0) ? e0 : ((kk == 1) ? e1 : e2);
  return __builtin_amdgcn_readlane(v, w & 63);
}
__device__ __forceinline__ u64 read_al3(u64 a0, u64 a1, u64 a2, int w) {
  const int kk = w >> 6;
  const u64 v = (kk == 0) ? a0 : ((kk == 1) ? a1 : a2);
  return rl64v(v, w & 63);
}

#define NMS_PF(cc, dgv, mv)                                                     \
  do {                                                                          \
    if ((cc) < NWORDS) {                                                        \
      dgv = maskT[(size_t)(cc) * NBOX + (size_t)(cc) * 64 + l];                 \
      const int epf_ = read_ext3(ex0, ex1, ex2, (cc));                          \
      const int tpf_ = (cc) + 1 + wsub;                                         \
      if (tpf_ <= epf_) {                                                       \
        const u64* ppf_ = maskT + (size_t)tpf_ * NBOX + (size_t)(cc) * 64 + sub * 8; \
        mv[0] = ppf_[0]; mv[1] = ppf_[1]; mv[2] = ppf_[2]; mv[3] = ppf_[3];     \
        mv[4] = ppf_[4]; mv[5] = ppf_[5]; mv[6] = ppf_[6]; mv[7] = ppf_[7];     \
      }                                                                         \
    }                                                                           \
  } while (0)

#define NMS_UPD(alK, K)                                                         \
  do {                                                                          \
    const int wq_ = (K) * 64 + l;                                               \
    const int gq_ = wq_ - c_ - 1;                                               \
    const u64 sq_ = shfl64(supF_, (gq_ & 7) * 8);                               \
    u64 rem_ = 0ull;                                                            \
    if (wq_ == c_) rem_ = supp_;                                                \
    else if ((unsigned)gq_ < 8u) rem_ = sq_;                                    \
    alK &= ~rem_;                                                               \
  } while (0)

#define NMS_UPDOV(alK, K)                                                       \
  do {                                                                          \
    const int wq_ = (K) * 64 + l;                                               \
    const int gq_ = wq_ - bb_;                                                  \
    const u64 sq_ = shfl64(sF_, (gq_ & 7) * 8);                                 \
    if ((unsigned)gq_ < 8u) alK &= ~sq_;                                        \
  } while (0)

#define NMS_STEP(c, dgv, mv, dgp, mp)                                           \
  do {                                                                          \
    const int c_ = (c);                                                         \
    NMS_PF(c_ + 3, dgp, mp); /* prefetch 3 iterations ahead */                  \
    const u64 aw0_ = read_al3(al0, al1, al2, c_);                               \
    if (aw0_) {                                                                 \
      const int e_ = read_ext3(ex0, ex1, ex2, c_);                              \
      /* phase A: intra-word greedy via S-ballot */                             \
      const bool sb_ = ((aw0_ >> l) & 1ull) && ((dgv & aw0_) != 0ull);          \
      u64 Sb_ = __ballot(sb_ ? 1 : 0);                                          \
      u64 supp_ = 0ull;                                                         \
      while (Sb_) {                                                             \
        const u64 p0_ = Sb_;                                                    \
        const u64 p1_ = p0_ & (p0_ - 1);                                        \
        const u64 p2_ = p1_ & (p1_ - 1);                                        \
        const u64 p3_ = p2_ & (p2_ - 1);                                        \
        const int b0_ = __builtin_ctzll(p0_);                                   \
        const int b1_ = p1_ ? __builtin_ctzll(p1_) : 64;                        \
        const int b2_ = p2_ ? __builtin_ctzll(p2_) : 64;                        \
        const int b3_ = p3_ ? __builtin_ctzll(p3_) : 64;                        \
        const u64 r0_ = rl64v(dgv, b0_);                                        \
        const u64 r1_ = rl64v(dgv, b1_ & 63);                                   \
        const u64 r2_ = rl64v(dgv, b2_ & 63);                                   \
        const u64 r3_ = rl64v(dgv, b3_ & 63);                                   \
        u64 sp_ = supp_ | r0_;                                                  \
        u64 done_ = 1ull << b0_;                                                \
        const u64 k1_ = ((b1_ < 64) && !((sp_ >> (b1_ & 63)) & 1ull)) ? ~0ull : 0ull; \
        sp_ |= r1_ & k1_; done_ |= (1ull << (b1_ & 63)) & k1_;                  \
        const u64 k2_ = ((b2_ < 64) && !((sp_ >> (b2_ & 63)) & 1ull)) ? ~0ull : 0ull; \
        sp_ |= r2_ & k2_; done_ |= (1ull << (b2_ & 63)) & k2_;                  \
        const u64 k3_ = ((b3_ < 64) && !((sp_ >> (b3_ & 63)) & 1ull)) ? ~0ull : 0ull; \
        sp_ |= r3_ & k3_; done_ |= (1ull << (b3_ & 63)) & k3_;                  \
        supp_ = sp_;                                                            \
        Sb_ &= ~(sp_ | done_);                                                  \
      }                                                                         \
      const u64 aw_ = aw0_ & ~supp_;                                            \
      /* phase B: prefetched columns c+1..c+8 */                                \
      u64 supF_ = 0ull;                                                         \
      const int t0_ = c_ + 1 + wsub;                                            \
      if (t0_ <= e_) {                                                          \
        const unsigned oct_ = (unsigned)(aw_ >> (sub * 8)) & 0xffu;             \
        if (oct_ & 1u)   supF_ |= mv[0];                                        \
        if (oct_ & 2u)   supF_ |= mv[1];                                        \
        if (oct_ & 4u)   supF_ |= mv[2];                                        \
        if (oct_ & 8u)   supF_ |= mv[3];                                        \
        if (oct_ & 16u)  supF_ |= mv[4];                                        \
        if (oct_ & 32u)  supF_ |= mv[5];                                        \
        if (oct_ & 64u)  supF_ |= mv[6];                                        \
        if (oct_ & 128u) supF_ |= mv[7];                                        \
      }                                                                         \
      supF_ |= shflxor64(supF_, 1);                                             \
      supF_ |= shflxor64(supF_, 2);                                             \
      supF_ |= shflxor64(supF_, 4);                                             \
      NMS_UPD(al0, 0); NMS_UPD(al1, 1); NMS_UPD(al2, 2);                        \
      /* overflow: columns beyond c+8 (rare) */                                 \
      for (int bb_ = c_ + 9; bb_ <= e_; bb_ += 8) {                             \
        const int tw_ = bb_ + wsub;                                             \
        u64 sF_ = 0ull;                                                         \
        if (tw_ <= e_) {                                                        \
          const u64* pov_ = maskT + (size_t)tw_ * NBOX + (size_t)c_ * 64 + sub * 8; \
          const unsigned oct_ = (unsigned)(aw_ >> (sub * 8)) & 0xffu;           \
          if (oct_ & 1u)   sF_ |= pov_[0];                                      \
          if (oct_ & 2u)   sF_ |= pov_[1];                                      \
          if (oct_ & 4u)   sF_ |= pov_[2];                                      \
          if (oct_ & 8u)   sF_ |= pov_[3];                                      \
          if (oct_ & 16u)  sF_ |= pov_[4];                                      \
          if (oct_ & 32u)  sF_ |= pov_[5];                                      \
          if (oct_ & 64u)  sF_ |= pov_[6];                                      \
          if (oct_ & 128u) sF_ |= pov_[7];                                      \
        }                                                                       \
        sF_ |= shflxor64(sF_, 1);                                               \
        sF_ |= shflxor64(sF_, 2);                                               \
        sF_ |= shflxor64(sF_, 4);                                               \
        NMS_UPDOV(al0, 0); NMS_UPDOV(al1, 1); NMS_UPDOV(al2, 2);                \
      }                                                                         \
    }                                                                           \
  } while (0)

__global__ __launch_bounds__(64) void nms_scan(
    const float* __restrict__ scores, const u64* __restrict__ maskT,
    const int* __restrict__ ext, u64* __restrict__ aliveOut)
{
  const int l = threadIdx.x;      // 0..63, single wave
  const int wsub = l >> 3;        // 0..7: downstream column offset
  const int sub = l & 7;          // 0..7: row-octet within that column

  // alive words + extents, fully in registers (lane l owns words l, l+64, l+128)
  u64 al0 = build_alive(scores + (size_t)l * 64);
  u64 al1 = build_alive(scores + (size_t)(64 + l) * 64);
  u64 al2 = build_alive(scores + (size_t)(128 + l) * 64);
  int ex0 = ext[l], ex1 = ext[64 + l], ex2 = ext[128 + l];

  u64 dg0 = 0, dg1 = 0, dg2 = 0, dg3 = 0;
  u64 m0[8], m1[8], m2[8], m3[8];
  #pragma unroll
  for (int j = 0; j < 8; ++j) { m0[j] = 0; m1[j] = 0; m2[j] = 0; m3[j] = 0; }

  // prologue: prefetch c = 0,1,2
  NMS_PF(0, dg0, m0);
  NMS_PF(1, dg1, m1);
  NMS_PF(2, dg2, m2);

  for (int cb = 0; cb < NWORDS; cb += 4) {
    NMS_STEP(cb + 0, dg0, m0, dg3, m3);
    NMS_STEP(cb + 1, dg1, m1, dg0, m0);
    NMS_STEP(cb + 2, dg2, m2, dg1, m1);
    NMS_STEP(cb + 3, dg3, m3, dg2, m2);
  }
  aliveOut[l] = al0;
  aliveOut[64 + l] = al1;
  aliveOut[128 + l] = al2;
}

// ---------------- Kernel 5: masked output ----------------
__global__ __launch_bounds__(256) void write_output(
    const float* __restrict__ boxes, const u64* __restrict__ alive,
    float* __restrict__ out)
{
  const int i = blockIdx.x * 256 + threadIdx.x;
  if (i < NBOX) {
    const bool k = (alive[i >> 6] >> (i & 63)) & 1ull;
    const float4 b = *(const float4*)&boxes[i * 4];
    const float4 z = {0.f, 0.f, 0.f, 0.f};
    *(float4*)&out[i * 4] = k ? b : z;
  }
}

extern "C" void kernel_launch(void* const* d_in, const int* in_sizes, int n_in,
                              void* d_out, int out_size, void* d_ws, size_t ws_size,
                              hipStream_t stream) {
  const float* X    = (const float*)d_in[0];  // (1,64,64,1024)
  const float* Wc   = (const float*)d_in[1];  // (3,3,1024,512)
  const float* Bc   = (const float*)d_in[2];  // (512,)
  const float* Wcls = (const float*)d_in[3];  // (1,1,512,6)
  const float* bcls = (const float*)d_in[4];  // (6,)
  const float* Wreg = (const float*)d_in[5];  // (1,1,512,12)
  const float* breg = (const float*)d_in[6];  // (12,)

  char* ws = (char*)d_ws;
  float*     Y      = (float*)    (ws);                 // 8,388,608 B (raw conv sums)
  float*     boxes  = (float*)    (ws + 8388608);       //   196,608 B
  float*     scores = (float*)    (ws + 8585216);       //    49,152 B
  u64*       aliveG = (u64*)      (ws + 8634368);       //     1,536 B
  int*       extG   = (int*)      (ws + 8635904);       //       768 B
  // conv phase uses [8,636,672 .. 27,511,040) for WTh+WTl; maskT reuses the
  // SAME region after conv is done (both exactly 18,874,368 B).
  _Float16*  WTh    = (_Float16*) (ws + 8636672);       // 9,437,184 B
  _Float16*  WTl    = (_Float16*) (ws + 18073856);      // 9,437,184 B
  u64*       maskT  = (u64*)      (ws + 8636672);       // 18,874,368 B (post-conv)

  zero_y      <<<2048, 256, 0, stream>>>((float4*)Y);
  prep_wt     <<<1152, 256, 0, stream>>>(Wc, WTh, WTl);
  conv_mfma   <<<256, 256, 0, stream>>>(X, WTh, WTl, Y);
  heads_decode<<<4096, 64, 0, stream>>>(Y, Bc, Wcls, bcls, Wreg, breg, boxes, scores, extG);
  build_mask  <<<dim3(192, 192), 256, 0, stream>>>(boxes, maskT, extG);
  nms_scan    <<<1, 64, 0, stream>>>(scores, maskT, extG, aliveG);
  write_output<<<48, 256, 0, stream>>>(boxes, aliveG, (float*)d_out);
}

// Round 4
// 794.911 us; speedup vs baseline: 1.0497x; 1.0497x over previous
//
#include <hip/hip_runtime.h>
#include <cstdint>

#define NBOX 12288
#define NWORDS 192
#define POS_THRESH 0.15f
#define NMS_THRESH 0.7f

typedef unsigned long long u64;
typedef _Float16 half8 __attribute__((ext_vector_type(8)));
typedef float floatx4 __attribute__((ext_vector_type(4)));

// ---------------- Kernel 0a: zero the conv accumulator ----------------
__global__ __launch_bounds__(256) void zero_y(float4* __restrict__ Y) {
  Y[blockIdx.x * 256 + threadIdx.x] = float4{0.f, 0.f, 0.f, 0.f};
}

// ---------------- Kernel 0b: W (3,3,1024,512) -> WT[tap][n][c] fp16 h/l split ----------------
// l pre-scaled by 4096 so it stays in fp16 normal range (w~0.01 -> wl~2e-6 would be denormal).
__global__ __launch_bounds__(256) void prep_wt(
    const float* __restrict__ Wc, _Float16* __restrict__ WTh, _Float16* __restrict__ WTl)
{
  __shared__ float tile[64][65];
  const int b = blockIdx.x;           // 9 taps * 16 c-tiles * 8 n-tiles = 1152
  const int tap = b >> 7;
  const int rem = b & 127;
  const int c0 = (rem >> 3) * 64, n0 = (rem & 7) * 64;
  const int t = threadIdx.x;
  #pragma unroll
  for (int i = 0; i < 16; ++i) {
    const int idx = i * 256 + t;
    const int c = idx >> 6, n = idx & 63;
    tile[n][c] = Wc[((size_t)(tap * 1024 + c0 + c)) * 512 + n0 + n];
  }
  __syncthreads();
  #pragma unroll
  for (int i = 0; i < 16; ++i) {
    const int idx = i * 256 + t;
    const int n = idx >> 6, c = idx & 63;
    const float v = tile[n][c];
    const _Float16 h = (_Float16)v;
    const _Float16 l = (_Float16)((v - (float)h) * 4096.0f);
    const size_t o = ((size_t)(tap * 512 + n0 + n)) * 1024 + c0 + c;
    WTh[o] = h;
    WTl[o] = l;
  }
}

// ---------------- Kernel 1: 3x3 conv via split-fp16 MFMA ----------------
#define AROW 40                 // 32 k-halves padded to 40 (80B = 20 banks: 2-way only)
#define AS_PLANE (4 * 66 * AROW)
#define BS_PLANE (128 * AROW)
__global__ __launch_bounds__(256, 1) void conv_mfma(
    const float* __restrict__ X, const _Float16* __restrict__ WTh,
    const _Float16* __restrict__ WTl, float* __restrict__ Y)
{
  __shared__ _Float16 As[2 * AS_PLANE];   // 42,240 B
  __shared__ _Float16 Bs[2 * BS_PLANE];   // 20,480 B
  const int bid = blockIdx.x;
  const int ks = bid & 1;
  const int nt = (bid >> 1) & 3;
  const int mt = bid >> 3;
  const int t = threadIdx.x;
  const int lane = t & 63, wid = t >> 6;
  const int wm = wid >> 1, wn = wid & 1;
  const int lrow = lane & 15, quad = lane >> 4;

  floatx4 accH[4][4], accL[4][4];
  #pragma unroll
  for (int i = 0; i < 4; ++i)
    #pragma unroll
    for (int j = 0; j < 4; ++j) { accH[i][j] = (floatx4)0.f; accL[i][j] = (floatx4)0.f; }

  for (int kc = 0; kc < 16; ++kc) {
    const int c0 = ks * 512 + kc * 32;
    __syncthreads();   // prior chunk readers done
    // ---- stage A halo: 264 (yy,xx) rows x 32 ch, split to h/l ----
    for (int r = t; r < 264; r += 256) {
      const int yy = r / 66;
      const int xx = r - yy * 66;
      const int yi = mt * 2 + yy - 1;
      const int xi = xx - 1;
      _Float16* dsth = &As[(yy * 66 + xx) * AROW];
      _Float16* dstl = dsth + AS_PLANE;
      if (yi >= 0 && yi < 64 && xi >= 0 && xi < 64) {
        const float4* src = (const float4*)(X + ((size_t)(yi * 64 + xi)) * 1024 + c0);
        #pragma unroll
        for (int j = 0; j < 4; ++j) {
          const float4 va = src[2 * j], vb = src[2 * j + 1];
          const float f[8] = {va.x, va.y, va.z, va.w, vb.x, vb.y, vb.z, vb.w};
          half8 hh, hl;
          #pragma unroll
          for (int e = 0; e < 8; ++e) {
            const _Float16 h = (_Float16)f[e];
            hh[e] = h;
            hl[e] = (_Float16)((f[e] - (float)h) * 4096.0f);
          }
          *(half8*)&dsth[j * 8] = hh;
          *(half8*)&dstl[j * 8] = hl;
        }
      } else {
        const half8 z = (half8)(_Float16)0.f;
        #pragma unroll
        for (int j = 0; j < 4; ++j) { *(half8*)&dsth[j * 8] = z; *(half8*)&dstl[j * 8] = z; }
      }
    }
    for (int tap = 0; tap < 9; ++tap) {
      if (tap > 0) __syncthreads();   // prior tap's B readers done
      {   // ---- stage B: 256 rows (hl,n) x 32 halves ----
        const int hl = t >> 7, n = t & 127;
        const _Float16* src = (hl ? WTl : WTh) +
            ((size_t)(tap * 512 + nt * 128 + n)) * 1024 + c0;
        _Float16* dst = &Bs[hl * BS_PLANE + n * AROW];
        #pragma unroll
        for (int j = 0; j < 4; ++j)
          *(half8*)&dst[j * 8] = *(const half8*)&src[j * 8];
      }
      __syncthreads();   // A (first tap) + B visible
      const int dy = tap / 3 - 1, dx = tap - (tap / 3) * 3 - 1;
      const int yy = wm + dy + 1;
      const int xxb = dx + 1;
      half8 Ah[4], Al[4], Bh[4], Bl[4];
      #pragma unroll
      for (int fm = 0; fm < 4; ++fm) {
        const int idx = (yy * 66 + xxb + fm * 16 + lrow) * AROW + quad * 8;
        Ah[fm] = *(const half8*)&As[idx];
        Al[fm] = *(const half8*)&As[idx + AS_PLANE];
      }
      #pragma unroll
      for (int fn = 0; fn < 4; ++fn) {
        const int idx = (wn * 64 + fn * 16 + lrow) * AROW + quad * 8;
        Bh[fn] = *(const half8*)&Bs[idx];
        Bl[fn] = *(const half8*)&Bs[idx + BS_PLANE];
      }
      #pragma unroll
      for (int fm = 0; fm < 4; ++fm)
        #pragma unroll
        for (int fn = 0; fn < 4; ++fn) {
          accH[fm][fn] = __builtin_amdgcn_mfma_f32_16x16x32_f16(Ah[fm], Bh[fn], accH[fm][fn], 0, 0, 0);
          accL[fm][fn] = __builtin_amdgcn_mfma_f32_16x16x32_f16(Al[fm], Bh[fn], accL[fm][fn], 0, 0, 0);
          accL[fm][fn] = __builtin_amdgcn_mfma_f32_16x16x32_f16(Ah[fm], Bl[fn], accL[fm][fn], 0, 0, 0);
        }
    }
  }
  // ---- epilogue: combine scales, atomic-accumulate (2 K-slices per output) ----
  const int m0 = mt * 128 + wm * 64;
  const int n0 = nt * 128 + wn * 64;
  #pragma unroll
  for (int fm = 0; fm < 4; ++fm)
    #pragma unroll
    for (int fn = 0; fn < 4; ++fn) {
      const int n = n0 + fn * 16 + lrow;
      #pragma unroll
      for (int r = 0; r < 4; ++r) {
        const int m = m0 + fm * 16 + quad * 4 + r;
        atomicAdd(&Y[(size_t)m * 512 + n],
                  accH[fm][fn][r] + accL[fm][fn][r] * (1.0f / 4096.0f));
      }
    }
}

// ---------------- Kernel 2: bias+ReLU + 1x1 heads + softmax(6) + decode + ext init ----------------
__global__ __launch_bounds__(64) void heads_decode(
    const float* __restrict__ Yx, const float* __restrict__ Bc,
    const float* __restrict__ Wcls, const float* __restrict__ bcls,
    const float* __restrict__ Wreg, const float* __restrict__ breg,
    float* __restrict__ boxes, float* __restrict__ scores, int* __restrict__ ext)
{
  __shared__ float xs[512];
  const int pos = blockIdx.x;
  const int l = threadIdx.x;
  if (l == 0 && pos < NWORDS) ext[pos] = pos;
  const float* xrow = Yx + (size_t)pos * 512;
  float4 v0 = *(const float4*)&xrow[l * 8];
  float4 v1 = *(const float4*)&xrow[l * 8 + 4];
  const float4 b0 = *(const float4*)&Bc[l * 8];
  const float4 b1 = *(const float4*)&Bc[l * 8 + 4];
  xs[l * 8 + 0] = fmaxf(v0.x + b0.x, 0.f);
  xs[l * 8 + 1] = fmaxf(v0.y + b0.y, 0.f);
  xs[l * 8 + 2] = fmaxf(v0.z + b0.z, 0.f);
  xs[l * 8 + 3] = fmaxf(v0.w + b0.w, 0.f);
  xs[l * 8 + 4] = fmaxf(v1.x + b1.x, 0.f);
  xs[l * 8 + 5] = fmaxf(v1.y + b1.y, 0.f);
  xs[l * 8 + 6] = fmaxf(v1.z + b1.z, 0.f);
  xs[l * 8 + 7] = fmaxf(v1.w + b1.w, 0.f);
  __syncthreads();

  const float* wp;
  int oc;
  float bini;
  if (l < 6)       { wp = Wcls + l;       oc = 6;  bini = bcls[l]; }
  else if (l < 18) { wp = Wreg + (l - 6); oc = 12; bini = breg[l - 6]; }
  else             { wp = Wcls;           oc = 0;  bini = 0.f; }
  float acc = bini;
  const float* p = wp;
  #pragma unroll 4
  for (int c = 0; c < 512; ++c) { acc = fmaf(xs[c], *p, acc); p += oc; }

  const float l0 = __shfl(acc, 0), l1 = __shfl(acc, 1), l2 = __shfl(acc, 2);
  const float l3 = __shfl(acc, 3), l4 = __shfl(acc, 4), l5 = __shfl(acc, 5);
  const int a = (l < 3) ? l : 0;
  const float d0 = __shfl(acc, 6 + a * 4 + 0);
  const float d1 = __shfl(acc, 6 + a * 4 + 1);
  const float d2 = __shfl(acc, 6 + a * 4 + 2);
  const float d3 = __shfl(acc, 6 + a * 4 + 3);

  const float mx = fmaxf(fmaxf(fmaxf(l0, l1), fmaxf(l2, l3)), fmaxf(l4, l5));
  const float e0 = expf(l0 - mx), e1 = expf(l1 - mx), e2 = expf(l2 - mx);
  const float e3 = expf(l3 - mx), e4 = expf(l4 - mx), e5 = expf(l5 - mx);
  const float den = ((((e0 + e1) + e2) + e3) + e4) + e5;
  const float esel = (a == 0) ? e1 : ((a == 1) ? e3 : e5);
  const float sc = esel / den;

  const int px = pos & 63, py = pos >> 6;
  const float cx = (px + 0.5f) * 16.0f;
  const float cy = (py + 0.5f) * 16.0f;
  const float ratio = (a == 0) ? 0.5f : ((a == 1) ? 1.0f : 2.0f);
  const float sq = sqrtf(ratio);
  const float wsz = 128.0f * sq;
  const float hsz = 128.0f / sq;
  const float a0 = cx - wsz * 0.5f;
  const float a1 = cy - hsz * 0.5f;
  const float a2 = cx + wsz * 0.5f;
  const float a3 = cy + hsz * 0.5f;
  const float w = a2 - a0, h = a3 - a1;
  const float xc = __fadd_rn(__fmul_rn(__fadd_rn(a0, a2), 0.5f), __fmul_rn(d0, w));
  const float yc = __fadd_rn(__fmul_rn(__fadd_rn(a1, a3), 0.5f), __fmul_rn(d1, h));
  const float nw = __fmul_rn(w, expf(d2));
  const float nh = __fmul_rn(h, expf(d3));
  float4 box;
  box.x = __fsub_rn(xc, __fmul_rn(nw, 0.5f));
  box.y = __fsub_rn(yc, __fmul_rn(nh, 0.5f));
  box.z = __fadd_rn(xc, __fmul_rn(nw, 0.5f));
  box.w = __fadd_rn(yc, __fmul_rn(nh, 0.5f));

  if (l < 3) {
    const int idx = pos * 3 + a;
    *(float4*)&boxes[idx * 4] = box;
    scores[idx] = sc;
  }
}

// ---------------- Kernel 3: suppression bit-matrix (column-major) + extent ----------------
__global__ __launch_bounds__(256) void build_mask(
    const float* __restrict__ boxes, u64* __restrict__ maskT,
    int* __restrict__ ext)
{
  const int w  = blockIdx.x;
  const int ci = blockIdx.y;
  if (w < ci) return;
  __shared__ float4 rb[64];
  __shared__ int anyf;
  const int t = threadIdx.x;
  const int lane = t & 63, wid = t >> 6;
  if (t == 0) anyf = 0;
  if (t < 64) rb[t] = *(const float4*)&boxes[(ci * 64 + t) * 4];
  const float4 cb = *(const float4*)&boxes[(w * 64 + lane) * 4];
  const float careaa = __fmul_rn(cb.z - cb.x, cb.w - cb.y);
  const int jglob = w * 64 + lane;
  __syncthreads();
  bool any = false;
  for (int rr = 0; rr < 16; ++rr) {
    const int r = wid * 16 + rr;
    const int row = ci * 64 + r;
    const float4 rx = rb[r];
    const float ra = __fmul_rn(rx.z - rx.x, rx.w - rx.y);
    const float xx1 = fmaxf(rx.x, cb.x);
    const float yy1 = fmaxf(rx.y, cb.y);
    const float xx2 = fminf(rx.z, cb.z);
    const float yy2 = fminf(rx.w, cb.w);
    const float iw = fmaxf(__fsub_rn(xx2, xx1), 0.f);
    const float ih = fmaxf(__fsub_rn(yy2, yy1), 0.f);
    const float inter = __fmul_rn(iw, ih);
    const float den = __fadd_rn(__fsub_rn(__fadd_rn(ra, careaa), inter), 1e-9f);
    const float iou = __fdiv_rn(inter, den);
    const bool bit = (iou > NMS_THRESH) && (jglob > row);
    any |= bit;
    const u64 word = __ballot(bit ? 1 : 0);
    if (lane == 0) maskT[(size_t)w * NBOX + row] = word;
  }
  if (any) anyf = 1;
  __syncthreads();
  if (t == 0 && anyf && w > ci) atomicMax(&ext[ci], w);
}

// ---------------- Kernel 4: sequential greedy NMS scan (single WAVE) ----------------
// v6 = v5 with BRANCHLESS prefetch: all 9 loads per step are unconditional with
// clamped addresses (usage gated later by t0<=ext in the octet select), so the
// compiler can emit counted s_waitcnt vmcnt(27) instead of conservative drains --
// the 3-step-ahead pipeline actually stays in flight. v5's conditional loads
// forced a full memory-latency stall every step (410us, VALUBusy 0.018).
__device__ __forceinline__ u64 rl64v(u64 v, int ln) {
  const unsigned a = (unsigned)__builtin_amdgcn_readlane((int)(unsigned)v, ln);
  const unsigned b = (unsigned)__builtin_amdgcn_readlane((int)(unsigned)(v >> 32), ln);
  return ((u64)b << 32) | (u64)a;
}
__device__ __forceinline__ u64 shfl64(u64 v, int src) {
  const int lo = __shfl((int)(unsigned)v, src);
  const int hi = __shfl((int)(unsigned)(v >> 32), src);
  return ((u64)(unsigned)hi << 32) | (unsigned)lo;
}
__device__ __forceinline__ u64 shflxor64(u64 v, int m) {
  const int lo = __shfl_xor((int)(unsigned)v, m);
  const int hi = __shfl_xor((int)(unsigned)(v >> 32), m);
  return ((u64)(unsigned)hi << 32) | (unsigned)lo;
}
__device__ __forceinline__ u64 build_alive(const float* sp) {
  u64 w = 0ull;
  const float4* p = (const float4*)sp;
  #pragma unroll
  for (int q = 0; q < 16; ++q) {
    const float4 s = p[q];
    if (s.x > POS_THRESH) w |= (1ull << (q * 4 + 0));
    if (s.y > POS_THRESH) w |= (1ull << (q * 4 + 1));
    if (s.z > POS_THRESH) w |= (1ull << (q * 4 + 2));
    if (s.w > POS_THRESH) w |= (1ull << (q * 4 + 3));
  }
  return w;
}
__device__ __forceinline__ int read_ext3(int e0, int e1, int e2, int w) {
  const int kk = w >> 6;
  const int v = (kk == 0) ? e0 : ((kk == 1) ? e1 : e2);
  return __builtin_amdgcn_readlane(v, w & 63);
}
__device__ __forceinline__ u64 read_al3(u64 a0, u64 a1, u64 a2, int w) {
  const int kk = w >> 6;
  const u64 v = (kk == 0) ? a0 : ((kk == 1) ? a1 : a2);
  return rl64v(v, w & 63);
}

// Unconditional prefetch with clamped addresses (branchless -> counted vmcnt).
#define NMS_PF(cc, dgv, mv)                                                     \
  do {                                                                          \
    const int cc_ = ((cc) < NWORDS - 1) ? (cc) : (NWORDS - 1);                  \
    dgv = maskT[(size_t)cc_ * NBOX + (size_t)cc_ * 64 + l];                     \
    const int tpfr_ = cc_ + 1 + wsub;                                           \
    const int tpf_ = (tpfr_ < NWORDS) ? tpfr_ : (NWORDS - 1);                   \
    const u64* ppf_ = maskT + (size_t)tpf_ * NBOX + (size_t)cc_ * 64 + sub * 8; \
    mv[0] = ppf_[0]; mv[1] = ppf_[1]; mv[2] = ppf_[2]; mv[3] = ppf_[3];         \
    mv[4] = ppf_[4]; mv[5] = ppf_[5]; mv[6] = ppf_[6]; mv[7] = ppf_[7];         \
  } while (0)

#define NMS_UPD(alK, K)                                                         \
  do {                                                                          \
    const int wq_ = (K) * 64 + l;                                               \
    const int gq_ = wq_ - c_ - 1;                                               \
    const u64 sq_ = shfl64(supF_, (gq_ & 7) * 8);                               \
    u64 rem_ = 0ull;                                                            \
    if (wq_ == c_) rem_ = supp_;                                                \
    else if ((unsigned)gq_ < 8u) rem_ = sq_;                                    \
    alK &= ~rem_;                                                               \
  } while (0)

#define NMS_UPDOV(alK, K)                                                       \
  do {                                                                          \
    const int wq_ = (K) * 64 + l;                                               \
    const int gq_ = wq_ - bb_;                                                  \
    const u64 sq_ = shfl64(sF_, (gq_ & 7) * 8);                                 \
    if ((unsigned)gq_ < 8u) alK &= ~sq_;                                        \
  } while (0)

#define NMS_STEP(c, dgv, mv, dgp, mp)                                           \
  do {                                                                          \
    const int c_ = (c);                                                         \
    NMS_PF(c_ + 3, dgp, mp); /* prefetch 3 iterations ahead */                  \
    const u64 aw0_ = read_al3(al0, al1, al2, c_);                               \
    if (aw0_) {                                                                 \
      const int e_ = read_ext3(ex0, ex1, ex2, c_);                              \
      /* phase A: intra-word greedy via S-ballot */                             \
      const bool sb_ = ((aw0_ >> l) & 1ull) && ((dgv & aw0_) != 0ull);          \
      u64 Sb_ = __ballot(sb_ ? 1 : 0);                                          \
      u64 supp_ = 0ull;                                                         \
      while (Sb_) {                                                             \
        const u64 p0_ = Sb_;                                                    \
        const u64 p1_ = p0_ & (p0_ - 1);                                        \
        const u64 p2_ = p1_ & (p1_ - 1);                                        \
        const u64 p3_ = p2_ & (p2_ - 1);                                        \
        const int b0_ = __builtin_ctzll(p0_);                                   \
        const int b1_ = p1_ ? __builtin_ctzll(p1_) : 64;                        \
        const int b2_ = p2_ ? __builtin_ctzll(p2_) : 64;                        \
        const int b3_ = p3_ ? __builtin_ctzll(p3_) : 64;                        \
        const u64 r0_ = rl64v(dgv, b0_);                                        \
        const u64 r1_ = rl64v(dgv, b1_ & 63);                                   \
        const u64 r2_ = rl64v(dgv, b2_ & 63);                                   \
        const u64 r3_ = rl64v(dgv, b3_ & 63);                                   \
        u64 sp_ = supp_ | r0_;                                                  \
        u64 done_ = 1ull << b0_;                                                \
        const u64 k1_ = ((b1_ < 64) && !((sp_ >> (b1_ & 63)) & 1ull)) ? ~0ull : 0ull; \
        sp_ |= r1_ & k1_; done_ |= (1ull << (b1_ & 63)) & k1_;                  \
        const u64 k2_ = ((b2_ < 64) && !((sp_ >> (b2_ & 63)) & 1ull)) ? ~0ull : 0ull; \
        sp_ |= r2_ & k2_; done_ |= (1ull << (b2_ & 63)) & k2_;                  \
        const u64 k3_ = ((b3_ < 64) && !((sp_ >> (b3_ & 63)) & 1ull)) ? ~0ull : 0ull; \
        sp_ |= r3_ & k3_; done_ |= (1ull << (b3_ & 63)) & k3_;                  \
        supp_ = sp_;                                                            \
        Sb_ &= ~(sp_ | done_);                                                  \
      }                                                                         \
      const u64 aw_ = aw0_ & ~supp_;                                            \
      /* phase B: prefetched columns c+1..c+8; usage gated here, not at load */ \
      const int t0_ = c_ + 1 + wsub;                                            \
      const unsigned gate_ = (t0_ <= e_) ? 0xffu : 0u;                          \
      const unsigned oct_ = ((unsigned)(aw_ >> (sub * 8)) & 0xffu) & gate_;     \
      u64 supF_ = 0ull;                                                         \
      if (oct_ & 1u)   supF_ |= mv[0];                                          \
      if (oct_ & 2u)   supF_ |= mv[1];                                          \
      if (oct_ & 4u)   supF_ |= mv[2];                                          \
      if (oct_ & 8u)   supF_ |= mv[3];                                          \
      if (oct_ & 16u)  supF_ |= mv[4];                                          \
      if (oct_ & 32u)  supF_ |= mv[5];                                          \
      if (oct_ & 64u)  supF_ |= mv[6];                                          \
      if (oct_ & 128u) supF_ |= mv[7];                                          \
      supF_ |= shflxor64(supF_, 1);                                             \
      supF_ |= shflxor64(supF_, 2);                                             \
      supF_ |= shflxor64(supF_, 4);                                             \
      NMS_UPD(al0, 0); NMS_UPD(al1, 1); NMS_UPD(al2, 2);                        \
      /* overflow: columns beyond c+8 (rare; uniform branch) */                 \
      for (int bb_ = c_ + 9; bb_ <= e_; bb_ += 8) {                             \
        const int tw_ = bb_ + wsub;                                             \
        u64 sF_ = 0ull;                                                         \
        if (tw_ <= e_) {                                                        \
          const u64* pov_ = maskT + (size_t)tw_ * NBOX + (size_t)c_ * 64 + sub * 8; \
          const unsigned octo_ = (unsigned)(aw_ >> (sub * 8)) & 0xffu;          \
          if (octo_ & 1u)   sF_ |= pov_[0];                                     \
          if (octo_ & 2u)   sF_ |= pov_[1];                                     \
          if (octo_ & 4u)   sF_ |= pov_[2];                                     \
          if (octo_ & 8u)   sF_ |= pov_[3];                                     \
          if (octo_ & 16u)  sF_ |= pov_[4];                                     \
          if (octo_ & 32u)  sF_ |= pov_[5];                                     \
          if (octo_ & 64u)  sF_ |= pov_[6];                                     \
          if (octo_ & 128u) sF_ |= pov_[7];                                     \
        }                                                                       \
        sF_ |= shflxor64(sF_, 1);                                               \
        sF_ |= shflxor64(sF_, 2);                                               \
        sF_ |= shflxor64(sF_, 4);                                               \
        NMS_UPDOV(al0, 0); NMS_UPDOV(al1, 1); NMS_UPDOV(al2, 2);                \
      }                                                                         \
    }                                                                           \
  } while (0)

__global__ __launch_bounds__(64) void nms_scan(
    const float* __restrict__ scores, const u64* __restrict__ maskT,
    const int* __restrict__ ext, u64* __restrict__ aliveOut)
{
  const int l = threadIdx.x;      // 0..63, single wave
  const int wsub = l >> 3;        // 0..7: downstream column offset
  const int sub = l & 7;          // 0..7: row-octet within that column

  // alive words + extents, fully in registers (lane l owns words l, l+64, l+128)
  u64 al0 = build_alive(scores + (size_t)l * 64);
  u64 al1 = build_alive(scores + (size_t)(64 + l) * 64);
  u64 al2 = build_alive(scores + (size_t)(128 + l) * 64);
  int ex0 = ext[l], ex1 = ext[64 + l], ex2 = ext[128 + l];

  u64 dg0 = 0, dg1 = 0, dg2 = 0, dg3 = 0;
  u64 m0[8], m1[8], m2[8], m3[8];

  // prologue: prefetch c = 0,1,2 (unconditional)
  NMS_PF(0, dg0, m0);
  NMS_PF(1, dg1, m1);
  NMS_PF(2, dg2, m2);

  for (int cb = 0; cb < NWORDS; cb += 4) {
    NMS_STEP(cb + 0, dg0, m0, dg3, m3);
    NMS_STEP(cb + 1, dg1, m1, dg0, m0);
    NMS_STEP(cb + 2, dg2, m2, dg1, m1);
    NMS_STEP(cb + 3, dg3, m3, dg2, m2);
  }
  aliveOut[l] = al0;
  aliveOut[64 + l] = al1;
  aliveOut[128 + l] = al2;
}

// ---------------- Kernel 5: masked output ----------------
__global__ __launch_bounds__(256) void write_output(
    const float* __restrict__ boxes, const u64* __restrict__ alive,
    float* __restrict__ out)
{
  const int i = blockIdx.x * 256 + threadIdx.x;
  if (i < NBOX) {
    const bool k = (alive[i >> 6] >> (i & 63)) & 1ull;
    const float4 b = *(const float4*)&boxes[i * 4];
    const float4 z = {0.f, 0.f, 0.f, 0.f};
    *(float4*)&out[i * 4] = k ? b : z;
  }
}

extern "C" void kernel_launch(void* const* d_in, const int* in_sizes, int n_in,
                              void* d_out, int out_size, void* d_ws, size_t ws_size,
                              hipStream_t stream) {
  const float* X    = (const float*)d_in[0];  // (1,64,64,1024)
  const float* Wc   = (const float*)d_in[1];  // (3,3,1024,512)
  const float* Bc   = (const float*)d_in[2];  // (512,)
  const float* Wcls = (const float*)d_in[3];  // (1,1,512,6)
  const float* bcls = (const float*)d_in[4];  // (6,)
  const float* Wreg = (const float*)d_in[5];  // (1,1,512,12)
  const float* breg = (const float*)d_in[6];  // (12,)

  char* ws = (char*)d_ws;
  float*     Y      = (float*)    (ws);                 // 8,388,608 B (raw conv sums)
  float*     boxes  = (float*)    (ws + 8388608);       //   196,608 B
  float*     scores = (float*)    (ws + 8585216);       //    49,152 B
  u64*       aliveG = (u64*)      (ws + 8634368);       //     1,536 B
  int*       extG   = (int*)      (ws + 8635904);       //       768 B
  // conv phase uses [8,636,672 .. 27,511,040) for WTh+WTl; maskT reuses the
  // SAME region after conv is done (both exactly 18,874,368 B).
  _Float16*  WTh    = (_Float16*) (ws + 8636672);       // 9,437,184 B
  _Float16*  WTl    = (_Float16*) (ws + 18073856);      // 9,437,184 B
  u64*       maskT  = (u64*)      (ws + 8636672);       // 18,874,368 B (post-conv)

  zero_y      <<<2048, 256, 0, stream>>>((float4*)Y);
  prep_wt     <<<1152, 256, 0, stream>>>(Wc, WTh, WTl);
  conv_mfma   <<<256, 256, 0, stream>>>(X, WTh, WTl, Y);
  heads_decode<<<4096, 64, 0, stream>>>(Y, Bc, Wcls, bcls, Wreg, breg, boxes, scores, extG);
  build_mask  <<<dim3(192, 192), 256, 0, stream>>>(boxes, maskT, extG);
  nms_scan    <<<1, 64, 0, stream>>>(scores, maskT, extG, aliveG);
  write_output<<<48, 256, 0, stream>>>(boxes, aliveG, (float*)d_out);
}